// Round 5
// baseline (267.541 us; speedup 1.0000x reference)
//
#include <hip/hip_runtime.h>
#include <hip/hip_bf16.h>

typedef __attribute__((ext_vector_type(8))) short short8;
typedef __attribute__((ext_vector_type(4))) short short4v;
typedef __attribute__((ext_vector_type(4))) float f32x4;

__device__ __forceinline__ short f2bf(float f) {
  union { __hip_bfloat16 h; short s; } u;
  u.h = __float2bfloat16(f);
  return u.s;
}

// Swizzled LDS index (in shorts): row stride 64 shorts (128 B), XOR the
// 16B-slot bits with (row&7). Applied on both write and read side.
__device__ __forceinline__ int swz(int row, int scol) {
  return row * 64 + (scol ^ ((row & 7) << 3));
}

// Block LDS: W dbuf 2*[64][64] bf16 = 16 KB, aliased (after final barrier)
// by the epilogue staging region: 8 waves * 16 rows * 68 f32 * 4 B = 34816 B.
#define LDS_BYTES 34816
#define EP_STRIDE 68   // f32; 272 B rows keep b128 reads 16B-aligned, +4 bank skew

// C[512, N] = A_bf16[512, K] * W_f32[N, K]^T + bias    (BN = 64)
// 8 waves; wave w owns rows [w*64, w*64+64). Registers <= 128/wave so TWO
// blocks co-reside per CU -> TLP hides load latency (no lockstep exposure).
// Per step: A(ks0) loads, W issue, MFMA ks0 (vmcnt leaves W in flight),
// A(ks1) reusing the same regs, MFMA ks1, convert+commit W, barrier.
__device__ __forceinline__ void gemm_body(
    const short* __restrict__ A,
    const float* __restrict__ W,
    const float* __restrict__ bias,
    float* __restrict__ C,
    int K, int N, int nb)
{
  __shared__ __align__(16) char smem[LDS_BYTES];
  short* wlds = (short*)smem;

  const int t    = threadIdx.x;
  const int wave = t >> 6;
  const int lane = t & 63;
  const int l16  = lane & 15;
  const int lq   = lane >> 4;
  const int n0   = nb * 64;

  const int sv = t >> 3;           // W row 0..63
  const int sk = (t & 7) * 8;      // 8 f32 per thread per K-tile
  const float* wp = W + (size_t)(n0 + sv) * K + sk;

  f32x4 acc[4][4];
  #pragma unroll
  for (int i = 0; i < 4; ++i)
    #pragma unroll
    for (int j = 0; j < 4; ++j) {
      f32x4 z = {0.f, 0.f, 0.f, 0.f};
      acc[i][j] = z;
    }

  const short* aBase = A + (size_t)(wave * 64 + l16) * K + lq * 8;

  f32x4 w0, w1;
  // prologue: tile 0 -> lds buf 0
  w0 = *(const f32x4*)(wp);
  w1 = *(const f32x4*)(wp + 4);
  {
    short8 wb;
    #pragma unroll
    for (int i = 0; i < 8; ++i) wb[i] = f2bf(i < 4 ? w0[i] : w1[i - 4]);
    *(short8*)&wlds[swz(sv, sk)] = wb;
  }
  __syncthreads();

  const int nt = K >> 6;
  for (int tI = 0; tI < nt; ++tI) {
    const short* lbuf = wlds + (tI & 1) * 4096;
    const int kb = tI << 6;
    short8 a[4];

    // ---- k-subtile 0: A loads first, THEN W issue (vmcnt queue: [A,W],
    // so waiting for A keeps W in flight through the MFMA phase)
    #pragma unroll
    for (int mf = 0; mf < 4; ++mf)
      a[mf] = *(const short8*)(aBase + (size_t)mf * 16 * K + kb);
    if (tI + 1 < nt) {
      w0 = *(const f32x4*)(wp + (tI + 1) * 64);
      w1 = *(const f32x4*)(wp + (tI + 1) * 64 + 4);
    }
    #pragma unroll
    for (int nf = 0; nf < 4; ++nf) {
      short8 b = *(const short8*)&lbuf[swz(nf * 16 + l16, lq * 8)];
      #pragma unroll
      for (int mf = 0; mf < 4; ++mf)
        acc[mf][nf] = __builtin_amdgcn_mfma_f32_16x16x32_bf16(a[mf], b, acc[mf][nf], 0, 0, 0);
    }

    // ---- k-subtile 1 (same a registers, reused)
    #pragma unroll
    for (int mf = 0; mf < 4; ++mf)
      a[mf] = *(const short8*)(aBase + (size_t)mf * 16 * K + kb + 32);
    #pragma unroll
    for (int nf = 0; nf < 4; ++nf) {
      short8 b = *(const short8*)&lbuf[swz(nf * 16 + l16, 32 + lq * 8)];
      #pragma unroll
      for (int mf = 0; mf < 4; ++mf)
        acc[mf][nf] = __builtin_amdgcn_mfma_f32_16x16x32_bf16(a[mf], b, acc[mf][nf], 0, 0, 0);
    }

    // convert + commit next W tile into the other buffer
    if (tI + 1 < nt) {
      short* lw = wlds + ((tI + 1) & 1) * 4096;
      short8 wb;
      #pragma unroll
      for (int i = 0; i < 8; ++i) wb[i] = f2bf(i < 4 ? w0[i] : w1[i - 4]);
      *(short8*)&lw[swz(sv, sk)] = wb;
    }
    __syncthreads();
  }

  // ---- epilogue: LDS-transpose to full-line vector stores ----
  // acc layout: col = nf*16 + l16, row = mf*16 + lq*4 + r  [m89]
  float bvv[4];
  #pragma unroll
  for (int nf = 0; nf < 4; ++nf) bvv[nf] = bias[n0 + nf * 16 + l16];

  float* myep = (float*)(smem + wave * (16 * EP_STRIDE * 4));
  const int rr = lane >> 4;          // 0..3
  const int cc = (lane & 15) * 4;    // 0..60

  #pragma unroll
  for (int mf = 0; mf < 4; ++mf) {
    #pragma unroll
    for (int nf = 0; nf < 4; ++nf)
      #pragma unroll
      for (int r = 0; r < 4; ++r)
        myep[(lq * 4 + r) * EP_STRIDE + nf * 16 + l16] = acc[mf][nf][r] + bvv[nf];
    // wave-local write->read; compiler inserts lgkmcnt wait (same LDS object)
    #pragma unroll
    for (int i = 0; i < 4; ++i) {
      f32x4 v = *(const f32x4*)&myep[(i * 4 + rr) * EP_STRIDE + cc];
      *(f32x4*)&C[(size_t)(wave * 64 + mf * 16 + i * 4 + rr) * N + n0 + cc] = v;
    }
  }
}

__global__ __launch_bounds__(512, 4) void gru_gemms_kernel(
    const short* __restrict__ xbf, const short* __restrict__ hbf,
    const float* __restrict__ W_ih, const float* __restrict__ W_hh,
    const float* __restrict__ b_ih, const float* __restrict__ b_hh,
    float* __restrict__ gi, float* __restrict__ gh)
{
  const bool second = blockIdx.x >= 96;
  gemm_body(second ? hbf : xbf,
            second ? W_hh : W_ih,
            second ? b_hh : b_ih,
            second ? gh : gi,
            second ? 2048 : 1024,
            6144,
            second ? (int)blockIdx.x - 96 : (int)blockIdx.x);
}

__global__ __launch_bounds__(512, 4) void logits_kernel(
    const short* __restrict__ hnbf, const float* __restrict__ fc_W,
    const float* __restrict__ fc_b, float* __restrict__ out)
{
  gemm_body(hnbf, fc_W, fc_b, out, 2048, 32000, (int)blockIdx.x);
}

__global__ void prep_kernel(const int* __restrict__ idx,
                            const float* __restrict__ hid,
                            const float* __restrict__ emb,
                            short* __restrict__ xbf, short* __restrict__ hbf)
{
  int i = blockIdx.x * blockDim.x + threadIdx.x;
  const int NX = 512 * 1024 / 4;   // 131072 float4s of x
  const int NH = 512 * 2048 / 4;   // 262144 float4s of h
  if (i < NX) {
    int b = i >> 8;                // 256 float4 per emb row
    int c = (i & 255) << 2;
    int row = idx[b];
    f32x4 v = *(const f32x4*)(emb + (size_t)row * 1024 + c);
    short4v o;
    #pragma unroll
    for (int j = 0; j < 4; ++j) o[j] = f2bf(v[j]);
    *(short4v*)(xbf + (size_t)b * 1024 + c) = o;
  } else if (i < NX + NH) {
    int j2 = i - NX;
    f32x4 v = *(const f32x4*)(hid + (size_t)j2 * 4);
    short4v o;
    #pragma unroll
    for (int j = 0; j < 4; ++j) o[j] = f2bf(v[j]);
    *(short4v*)(hbf + (size_t)j2 * 4) = o;
  }
}

__global__ void gates_kernel(const float* __restrict__ gi,
                             const float* __restrict__ gh,
                             const float* __restrict__ hid,
                             float* __restrict__ hnew,
                             short* __restrict__ hnbf)
{
  int i = blockIdx.x * blockDim.x + threadIdx.x;   // 512*512 threads, 4 cols each
  int b = i >> 9;
  int c = (i & 511) << 2;
  size_t gbase = (size_t)b * 6144 + c;
  f32x4 gir = *(const f32x4*)(gi + gbase);
  f32x4 giz = *(const f32x4*)(gi + gbase + 2048);
  f32x4 gin = *(const f32x4*)(gi + gbase + 4096);
  f32x4 ghr = *(const f32x4*)(gh + gbase);
  f32x4 ghz = *(const f32x4*)(gh + gbase + 2048);
  f32x4 ghn = *(const f32x4*)(gh + gbase + 4096);
  f32x4 hv  = *(const f32x4*)(hid + (size_t)b * 2048 + c);
  f32x4 hn;
  short4v hb;
  #pragma unroll
  for (int j = 0; j < 4; ++j) {
    float r = 1.f / (1.f + __expf(-(gir[j] + ghr[j])));
    float z = 1.f / (1.f + __expf(-(giz[j] + ghz[j])));
    float n = tanhf(gin[j] + r * ghn[j]);
    float o = (1.f - z) * n + z * hv[j];
    hn[j] = o;
    hb[j] = f2bf(o);
  }
  *(f32x4*)(hnew + (size_t)b * 2048 + c) = hn;
  *(short4v*)(hnbf + (size_t)b * 2048 + c) = hb;
}

extern "C" void kernel_launch(void* const* d_in, const int* in_sizes, int n_in,
                              void* d_out, int out_size, void* d_ws, size_t ws_size,
                              hipStream_t stream)
{
  const int*   idx   = (const int*)d_in[0];
  const float* hid   = (const float*)d_in[1];
  const float* emb   = (const float*)d_in[2];
  const float* W_ih  = (const float*)d_in[3];
  const float* W_hh  = (const float*)d_in[4];
  const float* b_ih  = (const float*)d_in[5];
  const float* b_hh  = (const float*)d_in[6];
  const float* fc_W  = (const float*)d_in[7];
  const float* fc_b  = (const float*)d_in[8];
  float* out = (float*)d_out;

  char* ws = (char*)d_ws;
  short* xbf  = (short*)(ws);                         // 512*1024 bf16 = 1 MB
  short* hbf  = (short*)(ws + 1048576);               // 512*2048 bf16 = 2 MB
  short* hnbf = (short*)(ws + 3145728);               // 512*2048 bf16 = 2 MB
  float* gi   = (float*)(ws + 5242880);               // 512*6144 f32 = 12.58 MB
  float* gh   = (float*)(ws + 17825792);              // 512*6144 f32 = 12.58 MB

  prep_kernel<<<1536, 256, 0, stream>>>(idx, hid, emb, xbf, hbf);
  gru_gemms_kernel<<<192, 512, 0, stream>>>(xbf, hbf, W_ih, W_hh, b_ih, b_hh, gi, gh);
  gates_kernel<<<1024, 256, 0, stream>>>(gi, gh, hid, out + (size_t)512 * 32000, hnbf);
  // N=32000 / BN=64 = 500 workgroups -> ~2 blocks/CU
  logits_kernel<<<500, 512, 0, stream>>>(hnbf, fc_W, fc_b, out);
}